// Round 1
// baseline (415173.242 us; speedup 1.0000x reference)
//
#include <hip/hip_runtime.h>
#include <cstddef>

#define S_LEN 16384
#define DIM   400
#define HID   256
#define NTAG  12
#define TSTART 10
#define TSTOP  11
#define FNEG  -10000.0f

// scan weight partition (half2 pairs per row; 128 total = 256 f16 weights)
#define NV 100   // register-resident, k-major layout
#define NL 14    // LDS-resident
#define NG 14    // loop-invariant global loads (LICM -> registers)

typedef unsigned int   u32;
typedef unsigned short u16;
typedef _Float16 half2_t __attribute__((ext_vector_type(2)));

#if defined(__has_builtin)
# if __has_builtin(__builtin_amdgcn_fdot2)
#  define HAVE_FDOT2 1
# endif
#endif

__device__ __forceinline__ float fdot2f(u32 a, u32 b, float acc) {
#ifdef HAVE_FDOT2
  return __builtin_amdgcn_fdot2(__builtin_bit_cast(half2_t, a),
                                __builtin_bit_cast(half2_t, b), acc, false);
#else
  half2_t x = __builtin_bit_cast(half2_t, a);
  half2_t y = __builtin_bit_cast(half2_t, b);
  return acc + (float)x[0] * (float)y[0] + (float)x[1] * (float)y[1];
#endif
}

__device__ __forceinline__ float sigmoidf_(float x) {
  return 1.0f / (1.0f + __expf(-x));
}
__device__ __forceinline__ float tanhf_(float x) {
  // 1 - 2/(e^{2x}+1); saturates correctly for large |x|
  float e = __expf(2.0f * x);
  return 1.0f - 2.0f / (e + 1.0f);
}

// ---------------------------------------------------------------------------
// Pack Whh (f32 [1024,256]) -> half2 pairs in the scan kernel's layout.
// Region V: k<NV             -> off = k*1024 + r
// Region L/G: k>=NV          -> off = NV*1024 + (k-NV)*1024 + (r&511)*2 + (r>>9)
// ---------------------------------------------------------------------------
__global__ __launch_bounds__(256) void pack_whh(
    const float* __restrict__ W0f, const float* __restrict__ W0b,
    const float* __restrict__ W1f, const float* __restrict__ W1b,
    u32* __restrict__ Wpk)
{
  int id  = blockIdx.x * 256 + threadIdx.x;   // 4*131072 total
  int m   = id >> 17;
  int rem = id & 131071;
  int k   = rem >> 10;
  int r   = rem & 1023;
  const float* W = (m == 0) ? W0f : (m == 1) ? W0b : (m == 2) ? W1f : W1b;
  half2_t h;
  h[0] = (_Float16)W[r * HID + 2 * k];
  h[1] = (_Float16)W[r * HID + 2 * k + 1];
  int dst;
  if (k < NV) dst = k * 1024 + r;
  else        dst = NV * 1024 + (k - NV) * 1024 + ((r & 511) << 1) + (r >> 9);
  Wpk[(size_t)m * 131072 + dst] = __builtin_bit_cast(u32, h);
}

// ---------------------------------------------------------------------------
// Fused highway layer: out = g*relu(x@Wn^T+bn) + (1-g)*(x@Wl^T+bl),
// g = sigmoid(x@Wg^T+bg).  64x64 tile, BK=16, 256 thr, 4x4 per thread,
// three accumulators sharing one A tile.
// ---------------------------------------------------------------------------
__global__ __launch_bounds__(256) void hw_kernel(
    const float* __restrict__ A,
    const float* __restrict__ Wgw, const float* __restrict__ bgw,
    const float* __restrict__ Wnw, const float* __restrict__ bnw,
    const float* __restrict__ Wlw, const float* __restrict__ blw,
    float* __restrict__ outp)
{
  __shared__ float As[16][68];
  __shared__ float Gs[16][68];
  __shared__ float Ns[16][68];
  __shared__ float Ls[16][68];
  const int tid = threadIdx.x;
  const int bm0 = blockIdx.x * 64;
  const int bn0 = blockIdx.y * 64;
  const int lr  = tid >> 2;
  const int lk  = (tid & 3) << 2;
  const int tx  = tid & 15, ty = tid >> 4;
  float aG[4][4], aN[4][4], aL[4][4];
#pragma unroll
  for (int i = 0; i < 4; ++i)
#pragma unroll
    for (int j = 0; j < 4; ++j) { aG[i][j] = 0.f; aN[i][j] = 0.f; aL[i][j] = 0.f; }

  for (int k0 = 0; k0 < DIM; k0 += 16) {
    float4 av = *(const float4*)(A + (size_t)(bm0 + lr) * DIM + k0 + lk);
    int wn = bn0 + lr;
    float4 gv = make_float4(0.f, 0.f, 0.f, 0.f);
    float4 nv = gv, lv = gv;
    if (wn < DIM) {
      gv = *(const float4*)(Wgw + (size_t)wn * DIM + k0 + lk);
      nv = *(const float4*)(Wnw + (size_t)wn * DIM + k0 + lk);
      lv = *(const float4*)(Wlw + (size_t)wn * DIM + k0 + lk);
    }
    __syncthreads();
    As[lk + 0][lr] = av.x; As[lk + 1][lr] = av.y; As[lk + 2][lr] = av.z; As[lk + 3][lr] = av.w;
    Gs[lk + 0][lr] = gv.x; Gs[lk + 1][lr] = gv.y; Gs[lk + 2][lr] = gv.z; Gs[lk + 3][lr] = gv.w;
    Ns[lk + 0][lr] = nv.x; Ns[lk + 1][lr] = nv.y; Ns[lk + 2][lr] = nv.z; Ns[lk + 3][lr] = nv.w;
    Ls[lk + 0][lr] = lv.x; Ls[lk + 1][lr] = lv.y; Ls[lk + 2][lr] = lv.z; Ls[lk + 3][lr] = lv.w;
    __syncthreads();
#pragma unroll
    for (int kk = 0; kk < 16; ++kk) {
      float a[4], g[4], n[4], l[4];
#pragma unroll
      for (int i = 0; i < 4; ++i) a[i] = As[kk][ty * 4 + i];
#pragma unroll
      for (int j = 0; j < 4; ++j) { g[j] = Gs[kk][tx * 4 + j]; n[j] = Ns[kk][tx * 4 + j]; l[j] = Ls[kk][tx * 4 + j]; }
#pragma unroll
      for (int i = 0; i < 4; ++i)
#pragma unroll
        for (int j = 0; j < 4; ++j) {
          aG[i][j] += a[i] * g[j];
          aN[i][j] += a[i] * n[j];
          aL[i][j] += a[i] * l[j];
        }
    }
  }
#pragma unroll
  for (int j = 0; j < 4; ++j) {
    int n = bn0 + tx * 4 + j;
    if (n >= DIM) continue;
    float bgv = bgw[n], bnv = bnw[n], blv = blw[n];
#pragma unroll
    for (int i = 0; i < 4; ++i) {
      int m = bm0 + ty * 4 + i;
      float gg = sigmoidf_(aG[i][j] + bgv);
      float nn = fmaxf(aN[i][j] + bnv, 0.f);
      float ll = aL[i][j] + blv;
      outp[(size_t)m * DIM + n] = gg * nn + (1.f - gg) * ll;
    }
  }
}

// ---------------------------------------------------------------------------
// Generic GEMM: C[m,n] = A[m,:K] . W[n,:K] + bias[n].  A:[M,K], W:[N,K] both
// row-major (K contiguous).  Stores f32 (outF) or f16 (outH).
// ---------------------------------------------------------------------------
__global__ __launch_bounds__(256) void gemm_kernel(
    const float* __restrict__ A, const float* __restrict__ W,
    const float* __restrict__ bias,
    float* __restrict__ outF, u16* __restrict__ outH,
    int M, int N, int K)
{
  __shared__ float As[16][68];
  __shared__ float Ws[16][68];
  const int tid = threadIdx.x;
  const int bm0 = blockIdx.x * 64;
  const int bn0 = blockIdx.y * 64;
  const int lr  = tid >> 2;
  const int lk  = (tid & 3) << 2;
  const int tx  = tid & 15, ty = tid >> 4;
  float acc[4][4];
#pragma unroll
  for (int i = 0; i < 4; ++i)
#pragma unroll
    for (int j = 0; j < 4; ++j) acc[i][j] = 0.f;

  for (int k0 = 0; k0 < K; k0 += 16) {
    float4 av = *(const float4*)(A + (size_t)(bm0 + lr) * K + k0 + lk);
    float4 wv = make_float4(0.f, 0.f, 0.f, 0.f);
    if (bn0 + lr < N) wv = *(const float4*)(W + (size_t)(bn0 + lr) * K + k0 + lk);
    __syncthreads();
    As[lk + 0][lr] = av.x; As[lk + 1][lr] = av.y; As[lk + 2][lr] = av.z; As[lk + 3][lr] = av.w;
    Ws[lk + 0][lr] = wv.x; Ws[lk + 1][lr] = wv.y; Ws[lk + 2][lr] = wv.z; Ws[lk + 3][lr] = wv.w;
    __syncthreads();
#pragma unroll
    for (int kk = 0; kk < 16; ++kk) {
      float a[4], w[4];
#pragma unroll
      for (int i = 0; i < 4; ++i) a[i] = As[kk][ty * 4 + i];
#pragma unroll
      for (int j = 0; j < 4; ++j) w[j] = Ws[kk][tx * 4 + j];
#pragma unroll
      for (int i = 0; i < 4; ++i)
#pragma unroll
        for (int j = 0; j < 4; ++j) acc[i][j] += a[i] * w[j];
    }
  }
#pragma unroll
  for (int j = 0; j < 4; ++j) {
    int n = bn0 + tx * 4 + j;
    if (n >= N) continue;
    float bv = bias ? bias[n] : 0.f;
#pragma unroll
    for (int i = 0; i < 4; ++i) {
      int m = bm0 + ty * 4 + i;
      float v = acc[i][j] + bv;
      if (outH) outH[(size_t)m * N + n] = __builtin_bit_cast(u16, (_Float16)v);
      else      outF[(size_t)m * N + n] = v;
    }
  }
}

// ---------------------------------------------------------------------------
// LSTM scan, one direction per block (grid=2).  512 threads, thread tid owns
// gate rows tid and tid+512.  Whh as half2 pairs: NV in VGPRs, NL in LDS,
// NG loop-invariant global (hoisted to regs).  h broadcast via LDS f16.
// ---------------------------------------------------------------------------
__global__ __launch_bounds__(512, 2) void lstm_scan(
    const u32* __restrict__ Wpk,       // [2 dirs][131072] packed for this layer
    const u16* __restrict__ P,         // [2][S][1024] f16: x@Wih^T + b
    const float* __restrict__ h0,
    const float* __restrict__ c0,
    int row_base,                      // 0 for layer0, 2 for layer1
    float* __restrict__ Xout)          // [S][512], this dir writes cols dir*256..
{
  const int dir = blockIdx.x;
  const int tid = threadIdx.x;
  const u32* Wd = Wpk + (size_t)dir * 131072u;

  __shared__ __align__(16) u32 lds_w[NL * 1024];   // 57344 B
  __shared__ float sA[512];
  __shared__ float sB[512];
  __shared__ __align__(16) u16 hbuf[256];

  // stage LDS-resident weights
  {
    const u32* Wl = Wd + NV * 1024;
#pragma unroll
    for (int i = 0; i < NL * 2; ++i)
      lds_w[i * 512 + tid] = Wl[i * 512 + tid];
  }
  // VGPR-resident weights
  u32 w0[NV], w1[NV];
#pragma unroll
  for (int k = 0; k < NV; ++k) {
    w0[k] = Wd[k * 1024 + tid];
    w1[k] = Wd[k * 1024 + tid + 512];
  }
  // loop-invariant global region -> registers
  uint2 wg[NG];
  {
    const uint2* WdG = (const uint2*)(Wd + (NV + NL) * 1024);
#pragma unroll
    for (int q = 0; q < NG; ++q) wg[q] = WdG[q * 512 + tid];
  }

  float c = 0.f;
  if (tid < 256) {
    c = c0[(row_base + dir) * HID + tid];
    float hv = h0[(row_base + dir) * HID + tid];
    hbuf[tid] = __builtin_bit_cast(u16, (_Float16)hv);
  }
  __syncthreads();

  const int t0 = dir ? (S_LEN - 1) : 0;
  const int dt = dir ? -1 : 1;
  const _Float16* pp = (const _Float16*)P + (size_t)dir * S_LEN * 1024
                       + (size_t)t0 * 1024 + tid;
  float* xp = Xout + (size_t)t0 * 512 + dir * HID + tid;
  const ptrdiff_t pstep = (ptrdiff_t)dt * 1024;
  const ptrdiff_t xstep = (ptrdiff_t)dt * 512;
  const uint2* lw2 = (const uint2*)lds_w;

  for (int s = 0; s < S_LEN; ++s) {
    float p0 = (float)pp[0];
    float p1 = (float)pp[512];
    pp += pstep;

    float a0 = 0.f, a1 = 0.f;
    const uint4* hb4 = (const uint4*)hbuf;
#pragma unroll
    for (int c4 = 0; c4 < 32; ++c4) {
      uint4 hq = hb4[c4];                      // wave-uniform broadcast read
      u32 hz[4] = {hq.x, hq.y, hq.z, hq.w};
#pragma unroll
      for (int j = 0; j < 4; ++j) {
        const int k = c4 * 4 + j;
        if (k < NV) {
          a0 = fdot2f(w0[k], hz[j], a0);
          a1 = fdot2f(w1[k], hz[j], a1);
        } else if (k < NV + NL) {
          uint2 wl = lw2[(k - NV) * 512 + tid];
          a0 = fdot2f(wl.x, hz[j], a0);
          a1 = fdot2f(wl.y, hz[j], a1);
        } else {
          uint2 wgl = wg[k - NV - NL];
          a0 = fdot2f(wgl.x, hz[j], a0);
          a1 = fdot2f(wgl.y, hz[j], a1);
        }
      }
    }
    a0 += p0; a1 += p1;

    // rows: [0,256)=i  [256,512)=f  [512,768)=g  [768,1024)=o
    float act0 = sigmoidf_(a0);
    float act1;
    if (tid < 256) act1 = tanhf_(a1);      // wave-uniform branch
    else           act1 = sigmoidf_(a1);
    sA[tid] = act0;
    sB[tid] = act1;
    __syncthreads();   // gates published; all hbuf reads of this step done

    if (tid < 256) {
      float iv  = sA[tid];
      float fv2 = sA[tid + 256];
      float gv  = sB[tid];
      float ov  = sB[tid + 256];
      c = fv2 * c + iv * gv;
      float hv = ov * tanhf_(c);
      hbuf[tid] = __builtin_bit_cast(u16, (_Float16)hv);
      *xp = hv;
    }
    xp += xstep;
    __syncthreads();   // new h visible before next step's dot loop
  }
}

// ---------------------------------------------------------------------------
// CRF: parallel log-semiring chunk products (128 chunks x 128 steps) + fold.
// M_t[i,j] = trans[i,j] + feat_t[i];  fv' = M (x) fv with (+)=logsumexp.
// ---------------------------------------------------------------------------
__global__ __launch_bounds__(192) void crf_chunk(
    const float* __restrict__ feats, const float* __restrict__ trans,
    float* __restrict__ Mc)
{
  __shared__ float tr[144];
  __shared__ float fb[128][12];
  __shared__ float accA[156];   // 12*13 padded
  __shared__ float accB[156];
  const int tid = threadIdx.x;
  const int cb  = blockIdx.x;
  if (tid < 144) tr[tid] = trans[tid];
  for (int i = tid; i < 128 * 12; i += 192)
    fb[i / 12][i % 12] = feats[(size_t)cb * 128 * 12 + i];
  __syncthreads();

  const int ii = tid / 12, jj = tid % 12;
  const bool act = tid < 144;
  float* cur = accA;
  float* nxt = accB;
  if (act) cur[ii * 13 + jj] = tr[ii * 12 + jj] + fb[0][ii];
  __syncthreads();

  for (int t = 1; t < 128; ++t) {
    if (act) {
      float v[12];
      float m = FNEG * 4.f;
#pragma unroll
      for (int k = 0; k < 12; ++k) {
        v[k] = tr[ii * 12 + k] + cur[k * 13 + jj];
        m = fmaxf(m, v[k]);
      }
      float ssum = 0.f;
#pragma unroll
      for (int k = 0; k < 12; ++k) ssum += __expf(v[k] - m);
      nxt[ii * 13 + jj] = fb[t][ii] + m + __logf(ssum);
    }
    __syncthreads();
    float* tmp = cur; cur = nxt; nxt = tmp;
  }
  if (act) Mc[(size_t)cb * 144 + ii * 12 + jj] = cur[ii * 13 + jj];
}

__global__ __launch_bounds__(64) void crf_fold(
    const float* __restrict__ Mc, const float* __restrict__ trans,
    float* __restrict__ outp)
{
  __shared__ float fv[12];
  __shared__ float nf[12];
  const int tid = threadIdx.x;
  if (tid < 12) fv[tid] = (tid == TSTART) ? 0.f : FNEG;
  __syncthreads();
  for (int cidx = 0; cidx < 128; ++cidx) {
    if (tid < 12) {
      const float* M = Mc + (size_t)cidx * 144 + tid * 12;
      float v[12];
      float m = FNEG * 4.f;
#pragma unroll
      for (int j = 0; j < 12; ++j) {
        v[j] = M[j] + fv[j];
        m = fmaxf(m, v[j]);
      }
      float s = 0.f;
#pragma unroll
      for (int j = 0; j < 12; ++j) s += __expf(v[j] - m);
      nf[tid] = m + __logf(s);
    }
    __syncthreads();
    if (tid < 12) fv[tid] = nf[tid];
    __syncthreads();
  }
  if (tid == 0) {
    float v[12];
    float m = FNEG * 4.f;
#pragma unroll
    for (int i = 0; i < 12; ++i) {
      v[i] = fv[i] + trans[TSTOP * 12 + i];
      m = fmaxf(m, v[i]);
    }
    float s = 0.f;
#pragma unroll
    for (int i = 0; i < 12; ++i) s += __expf(v[i] - m);
    outp[0] = m + __logf(s);
  }
}

// ---------------------------------------------------------------------------
extern "C" void kernel_launch(void* const* d_in, const int* in_sizes, int n_in,
                              void* d_out, int out_size, void* d_ws, size_t ws_size,
                              hipStream_t stream)
{
  (void)in_sizes; (void)n_in; (void)out_size; (void)ws_size;
  const float* x     = (const float*)d_in[0];
  const float* Wg    = (const float*)d_in[1];
  const float* bg    = (const float*)d_in[2];
  const float* Wn    = (const float*)d_in[3];
  const float* bnn   = (const float*)d_in[4];
  const float* Wl    = (const float*)d_in[5];
  const float* bl    = (const float*)d_in[6];
  const float* Wih0f = (const float*)d_in[7];
  const float* Whh0f = (const float*)d_in[8];
  const float* b0f   = (const float*)d_in[9];
  const float* Wih0b = (const float*)d_in[10];
  const float* Whh0b = (const float*)d_in[11];
  const float* b0b   = (const float*)d_in[12];
  const float* Wih1f = (const float*)d_in[13];
  const float* Whh1f = (const float*)d_in[14];
  const float* b1f   = (const float*)d_in[15];
  const float* Wih1b = (const float*)d_in[16];
  const float* Whh1b = (const float*)d_in[17];
  const float* b1b   = (const float*)d_in[18];
  const float* Wtag  = (const float*)d_in[19];
  const float* btag  = (const float*)d_in[20];
  const float* trans = (const float*)d_in[21];
  const float* h0    = (const float*)d_in[22];
  const float* c0    = (const float*)d_in[23];

  char* ws = (char*)d_ws;
  size_t off = 0;
  auto alloc = [&](size_t bytes) -> void* {
    void* p = ws + off;
    off += (bytes + 255) & ~(size_t)255;
    return p;
  };
  float* xhw1  = (float*)alloc((size_t)S_LEN * DIM * 4);        // 26.2 MB
  float* xhw2  = (float*)alloc((size_t)S_LEN * DIM * 4);        // 26.2 MB
  u16*   Pbuf  = (u16*)alloc((size_t)2 * S_LEN * 1024 * 2);     // 64 MB (reused layer0/1)
  float* X1    = (float*)alloc((size_t)S_LEN * 512 * 4);        // 33.6 MB (reused as LO)
  u32*   Wpk   = (u32*)alloc((size_t)4 * 131072 * 4);           // 2 MB
  float* feats = (float*)alloc((size_t)S_LEN * NTAG * 4);       // 0.8 MB
  float* Mc    = (float*)alloc((size_t)128 * 144 * 4);          // 74 KB
  // total ~153 MB

  // 1) pack recurrent weights to f16 pairs
  pack_whh<<<2048, 256, 0, stream>>>(Whh0f, Whh0b, Whh1f, Whh1b, Wpk);

  // 2) highway x2
  dim3 gHW(S_LEN / 64, 7);
  hw_kernel<<<gHW, 256, 0, stream>>>(x, Wg, bg, Wn, bnn, Wl, bl, xhw1);
  hw_kernel<<<gHW, 256, 0, stream>>>(xhw1, Wg + 160000, bg + 400,
                                     Wn + 160000, bnn + 400,
                                     Wl + 160000, bl + 400, xhw2);

  // 3) layer-0 input projections (f16 out)
  dim3 gP(S_LEN / 64, 16);
  gemm_kernel<<<gP, 256, 0, stream>>>(xhw2, Wih0f, b0f, nullptr, Pbuf,
                                      S_LEN, 1024, DIM);
  gemm_kernel<<<gP, 256, 0, stream>>>(xhw2, Wih0b, b0b, nullptr,
                                      Pbuf + (size_t)S_LEN * 1024,
                                      S_LEN, 1024, DIM);

  // 4) layer-0 bidirectional scan -> X1 [S,512]
  lstm_scan<<<2, 512, 0, stream>>>(Wpk, Pbuf, h0, c0, 0, X1);

  // 5) layer-1 input projections (Pbuf reused)
  gemm_kernel<<<gP, 256, 0, stream>>>(X1, Wih1f, b1f, nullptr, Pbuf,
                                      S_LEN, 1024, 512);
  gemm_kernel<<<gP, 256, 0, stream>>>(X1, Wih1b, b1b, nullptr,
                                      Pbuf + (size_t)S_LEN * 1024,
                                      S_LEN, 1024, 512);

  // 6) layer-1 scan -> X1 reused as lstm_out [S,512]
  lstm_scan<<<2, 512, 0, stream>>>(Wpk + 2 * 131072, Pbuf, h0, c0, 2, X1);

  // 7) tag projection -> feats [S,12]
  dim3 gT(S_LEN / 64, 1);
  gemm_kernel<<<gT, 256, 0, stream>>>(X1, Wtag, btag, feats, nullptr,
                                      S_LEN, NTAG, 512);

  // 8) CRF log-partition: parallel chunks + sequential fold
  crf_chunk<<<128, 192, 0, stream>>>(feats, trans, Mc);
  crf_fold<<<1, 64, 0, stream>>>(Mc, trans, (float*)d_out);
}

// Round 2
// 34595.889 us; speedup vs baseline: 12.0007x; 12.0007x over previous
//
#include <hip/hip_runtime.h>
#include <cstddef>

#define S_LEN 16384
#define DIM   400
#define HID   256
#define NTAG  12
#define TSTART 10
#define TSTOP  11
#define FNEG  -10000.0f

typedef unsigned int   u32;
typedef unsigned short u16;
typedef _Float16 half2_t __attribute__((ext_vector_type(2)));

__device__ __forceinline__ int sdot4f(u32 a, u32 b, int acc) {
#if defined(__has_builtin) && __has_builtin(__builtin_amdgcn_sdot4)
  return __builtin_amdgcn_sdot4((int)a, (int)b, acc, false);
#else
  #pragma unroll
  for (int i = 0; i < 4; ++i) {
    int ai = (int)(signed char)((a >> (8 * i)) & 255u);
    int bi = (int)(signed char)((b >> (8 * i)) & 255u);
    acc += ai * bi;
  }
  return acc;
#endif
}

__device__ __forceinline__ float sigmoidf_(float x) {
  return 1.0f / (1.0f + __expf(-x));
}
__device__ __forceinline__ float tanhf_(float x) {
  float e = __expf(2.0f * x);
  return 1.0f - 2.0f / (e + 1.0f);
}

// ---------------------------------------------------------------------------
// Quantize Whh rows (4 mats x 1024 rows x 256) and h0 (4 rows x 256) to int8
// with per-row scale.  One wave per row; lane l owns 4 consecutive floats ->
// one packed i32 word.  Grid covers 4100 rows.
// ---------------------------------------------------------------------------
__global__ __launch_bounds__(256) void quant_whh(
    const float* __restrict__ W0f, const float* __restrict__ W0b,
    const float* __restrict__ W1f, const float* __restrict__ W1b,
    const float* __restrict__ h0,
    int* __restrict__ Wq8, float* __restrict__ Wsc,
    int* __restrict__ h0q, float* __restrict__ h0s)
{
  const int wave = threadIdx.x >> 6;
  const int lane = threadIdx.x & 63;
  const int row  = blockIdx.x * 4 + wave;
  if (row >= 4100) return;
  const float* src;
  if (row < 4096) {
    int mat = row >> 10, r = row & 1023;
    const float* W = (mat == 0) ? W0f : (mat == 1) ? W0b : (mat == 2) ? W1f : W1b;
    src = W + (size_t)r * HID;
  } else {
    src = h0 + (size_t)(row - 4096) * HID;
  }
  float4 v = *(const float4*)(src + lane * 4);
  float m = fmaxf(fmaxf(fabsf(v.x), fabsf(v.y)), fmaxf(fabsf(v.z), fabsf(v.w)));
#pragma unroll
  for (int off = 32; off; off >>= 1) m = fmaxf(m, __shfl_xor(m, off, 64));
  float inv   = (m > 0.f) ? 127.f / m : 0.f;
  float scale = (m > 0.f) ? m / 127.f : 0.f;
  int q0 = (int)rintf(v.x * inv);
  int q1 = (int)rintf(v.y * inv);
  int q2 = (int)rintf(v.z * inv);
  int q3 = (int)rintf(v.w * inv);
  int packed = (q0 & 255) | ((q1 & 255) << 8) | ((q2 & 255) << 16) | ((q3 & 255) << 24);
  if (row < 4096) {
    Wq8[(size_t)row * 64 + lane] = packed;
    if (lane == 0) Wsc[row] = scale;
  } else {
    h0q[(size_t)(row - 4096) * 64 + lane] = packed;
    if (lane == 0) h0s[row - 4096] = scale;
  }
}

// ---------------------------------------------------------------------------
// Fused highway layer: out = g*relu(x@Wn^T+bn) + (1-g)*(x@Wl^T+bl)
// ---------------------------------------------------------------------------
__global__ __launch_bounds__(256) void hw_kernel(
    const float* __restrict__ A,
    const float* __restrict__ Wgw, const float* __restrict__ bgw,
    const float* __restrict__ Wnw, const float* __restrict__ bnw,
    const float* __restrict__ Wlw, const float* __restrict__ blw,
    float* __restrict__ outp)
{
  __shared__ float As[16][68];
  __shared__ float Gs[16][68];
  __shared__ float Ns[16][68];
  __shared__ float Ls[16][68];
  const int tid = threadIdx.x;
  const int bm0 = blockIdx.x * 64;
  const int bn0 = blockIdx.y * 64;
  const int lr  = tid >> 2;
  const int lk  = (tid & 3) << 2;
  const int tx  = tid & 15, ty = tid >> 4;
  float aG[4][4], aN[4][4], aL[4][4];
#pragma unroll
  for (int i = 0; i < 4; ++i)
#pragma unroll
    for (int j = 0; j < 4; ++j) { aG[i][j] = 0.f; aN[i][j] = 0.f; aL[i][j] = 0.f; }

  for (int k0 = 0; k0 < DIM; k0 += 16) {
    float4 av = *(const float4*)(A + (size_t)(bm0 + lr) * DIM + k0 + lk);
    int wn = bn0 + lr;
    float4 gv = make_float4(0.f, 0.f, 0.f, 0.f);
    float4 nv = gv, lv = gv;
    if (wn < DIM) {
      gv = *(const float4*)(Wgw + (size_t)wn * DIM + k0 + lk);
      nv = *(const float4*)(Wnw + (size_t)wn * DIM + k0 + lk);
      lv = *(const float4*)(Wlw + (size_t)wn * DIM + k0 + lk);
    }
    __syncthreads();
    As[lk + 0][lr] = av.x; As[lk + 1][lr] = av.y; As[lk + 2][lr] = av.z; As[lk + 3][lr] = av.w;
    Gs[lk + 0][lr] = gv.x; Gs[lk + 1][lr] = gv.y; Gs[lk + 2][lr] = gv.z; Gs[lk + 3][lr] = gv.w;
    Ns[lk + 0][lr] = nv.x; Ns[lk + 1][lr] = nv.y; Ns[lk + 2][lr] = nv.z; Ns[lk + 3][lr] = nv.w;
    Ls[lk + 0][lr] = lv.x; Ls[lk + 1][lr] = lv.y; Ls[lk + 2][lr] = lv.z; Ls[lk + 3][lr] = lv.w;
    __syncthreads();
#pragma unroll
    for (int kk = 0; kk < 16; ++kk) {
      float a[4], g[4], n[4], l[4];
#pragma unroll
      for (int i = 0; i < 4; ++i) a[i] = As[kk][ty * 4 + i];
#pragma unroll
      for (int j = 0; j < 4; ++j) { g[j] = Gs[kk][tx * 4 + j]; n[j] = Ns[kk][tx * 4 + j]; l[j] = Ls[kk][tx * 4 + j]; }
#pragma unroll
      for (int i = 0; i < 4; ++i)
#pragma unroll
        for (int j = 0; j < 4; ++j) {
          aG[i][j] += a[i] * g[j];
          aN[i][j] += a[i] * n[j];
          aL[i][j] += a[i] * l[j];
        }
    }
  }
#pragma unroll
  for (int j = 0; j < 4; ++j) {
    int n = bn0 + tx * 4 + j;
    if (n >= DIM) continue;
    float bgv = bgw[n], bnv = bnw[n], blv = blw[n];
#pragma unroll
    for (int i = 0; i < 4; ++i) {
      int m = bm0 + ty * 4 + i;
      float gg = sigmoidf_(aG[i][j] + bgv);
      float nn = fmaxf(aN[i][j] + bnv, 0.f);
      float ll = aL[i][j] + blv;
      outp[(size_t)m * DIM + n] = gg * nn + (1.f - gg) * ll;
    }
  }
}

// ---------------------------------------------------------------------------
// Generic GEMM: C[m,n] = A[m,:K] . W[n,:K] + bias[n]
// ---------------------------------------------------------------------------
__global__ __launch_bounds__(256) void gemm_kernel(
    const float* __restrict__ A, const float* __restrict__ W,
    const float* __restrict__ bias,
    float* __restrict__ outF, u16* __restrict__ outH,
    int M, int N, int K)
{
  __shared__ float As[16][68];
  __shared__ float Ws[16][68];
  const int tid = threadIdx.x;
  const int bm0 = blockIdx.x * 64;
  const int bn0 = blockIdx.y * 64;
  const int lr  = tid >> 2;
  const int lk  = (tid & 3) << 2;
  const int tx  = tid & 15, ty = tid >> 4;
  float acc[4][4];
#pragma unroll
  for (int i = 0; i < 4; ++i)
#pragma unroll
    for (int j = 0; j < 4; ++j) acc[i][j] = 0.f;

  for (int k0 = 0; k0 < K; k0 += 16) {
    float4 av = *(const float4*)(A + (size_t)(bm0 + lr) * K + k0 + lk);
    float4 wv = make_float4(0.f, 0.f, 0.f, 0.f);
    if (bn0 + lr < N) wv = *(const float4*)(W + (size_t)(bn0 + lr) * K + k0 + lk);
    __syncthreads();
    As[lk + 0][lr] = av.x; As[lk + 1][lr] = av.y; As[lk + 2][lr] = av.z; As[lk + 3][lr] = av.w;
    Ws[lk + 0][lr] = wv.x; Ws[lk + 1][lr] = wv.y; Ws[lk + 2][lr] = wv.z; Ws[lk + 3][lr] = wv.w;
    __syncthreads();
#pragma unroll
    for (int kk = 0; kk < 16; ++kk) {
      float a[4], w[4];
#pragma unroll
      for (int i = 0; i < 4; ++i) a[i] = As[kk][ty * 4 + i];
#pragma unroll
      for (int j = 0; j < 4; ++j) w[j] = Ws[kk][tx * 4 + j];
#pragma unroll
      for (int i = 0; i < 4; ++i)
#pragma unroll
        for (int j = 0; j < 4; ++j) acc[i][j] += a[i] * w[j];
    }
  }
#pragma unroll
  for (int j = 0; j < 4; ++j) {
    int n = bn0 + tx * 4 + j;
    if (n >= N) continue;
    float bv = bias ? bias[n] : 0.f;
#pragma unroll
    for (int i = 0; i < 4; ++i) {
      int m = bm0 + ty * 4 + i;
      float v = acc[i][j] + bv;
      if (outH) outH[(size_t)m * N + n] = __builtin_bit_cast(u16, (_Float16)v);
      else      outF[(size_t)m * N + n] = v;
    }
  }
}

// ---------------------------------------------------------------------------
// LSTM scan, one direction per block (grid=2).  512 threads; thread tid owns
// gate rows tid and tid+512.  Whh int8-quantized, 128 weight VGPRs/thread
// (uint4 wA[16]/wB[16], constant-indexed -> stays in registers).
// h broadcast as 256 int8 in LDS; 128 v_dot4_i32_i8 per thread per step.
// ---------------------------------------------------------------------------
__global__ __launch_bounds__(512, 1) void lstm_scan(
    const int* __restrict__ WqL,    // [2 dirs][1024][64] i32 words (this layer)
    const float* __restrict__ WscL, // [2 dirs][1024]
    const int* __restrict__ h0q,    // [4][64]
    const float* __restrict__ h0s,  // [4]
    const float* __restrict__ c0,   // [4][256]
    int row_base,
    const u16* __restrict__ P,      // [2][S][1024] f16: x@Wih^T + b
    float* __restrict__ Xout)       // [S][512]
{
  const int dir = blockIdx.x;
  const int tid = threadIdx.x;
  const int rowA = tid;
  const int rowB = tid + 512;

  __shared__ float sA[512];
  __shared__ float sB[512];
  __shared__ __align__(16) unsigned int hbuf[64];   // 256 int8

  uint4 wA[16], wB[16];
  {
    const uint4* pA = (const uint4*)(WqL + ((size_t)dir * 1024 + rowA) * 64);
    const uint4* pB = (const uint4*)(WqL + ((size_t)dir * 1024 + rowB) * 64);
#pragma unroll
    for (int q = 0; q < 16; ++q) { wA[q] = pA[q]; wB[q] = pB[q]; }
  }
  const float scA = WscL[dir * 1024 + rowA];
  const float scB = WscL[dir * 1024 + rowB];

  float c = 0.f;
  if (tid < 256) c = c0[(row_base + dir) * HID + tid];
  if (tid < 64)  hbuf[tid] = (unsigned int)h0q[(size_t)(row_base + dir) * 64 + tid];
  float hscale = h0s[row_base + dir];
  __syncthreads();

  const int t0 = dir ? (S_LEN - 1) : 0;
  const ptrdiff_t pstep = dir ? -1024 : 1024;
  const ptrdiff_t xstep = dir ? -512 : 512;
  const u16* pp = P + (size_t)dir * S_LEN * 1024 + (size_t)t0 * 1024 + tid;
  float* xp = Xout + (size_t)t0 * 512 + dir * HID + tid;

  u16 pc0 = pp[0];
  u16 pc1 = pp[512];

  for (int s = 0; s < S_LEN; ++s) {
    // software prefetch of next step's P (independent of h)
    const u16* ppn = (s < S_LEN - 1) ? (pp + pstep) : pp;
    u16 pn0 = ppn[0];
    u16 pn1 = ppn[512];

    int a0 = 0, a1 = 0;
    const uint4* hb4 = (const uint4*)hbuf;
#pragma unroll
    for (int q = 0; q < 16; ++q) {
      uint4 h4 = hb4[q];                 // wave-uniform broadcast read
      a0 = sdot4f(wA[q].x, h4.x, a0);
      a1 = sdot4f(wB[q].x, h4.x, a1);
      a0 = sdot4f(wA[q].y, h4.y, a0);
      a1 = sdot4f(wB[q].y, h4.y, a1);
      a0 = sdot4f(wA[q].z, h4.z, a0);
      a1 = sdot4f(wB[q].z, h4.z, a1);
      a0 = sdot4f(wA[q].w, h4.w, a0);
      a1 = sdot4f(wB[q].w, h4.w, a1);
    }
    float g0 = (float)a0 * (scA * hscale) + (float)__builtin_bit_cast(_Float16, pc0);
    float g1 = (float)a1 * (scB * hscale) + (float)__builtin_bit_cast(_Float16, pc1);

    // rows: [0,256)=i  [256,512)=f  [512,768)=g  [768,1024)=o
    float act0 = sigmoidf_(g0);
    float act1 = (tid < 256) ? tanhf_(g1) : sigmoidf_(g1);
    sA[tid] = act0;
    sB[tid] = act1;
    __syncthreads();   // gates published; hbuf reads of this step done

    if (tid < 256) {
      float iv = sA[tid], fv = sA[tid + 256], gv = sB[tid], ov = sB[tid + 256];
      c = fv * c + iv * gv;
      float hv = ov * tanhf_(c);
      ((signed char*)hbuf)[tid] = (signed char)(int)rintf(hv * 127.f);  // |hv|<1
      *xp = hv;
    }
    hscale = (1.f / 127.f);
    xp += xstep;
    pp = ppn; pc0 = pn0; pc1 = pn1;
    __syncthreads();   // new h visible before next step
  }
}

// ---------------------------------------------------------------------------
// CRF: parallel log-semiring chunk products (128 chunks x 128 steps) + fold.
// ---------------------------------------------------------------------------
__global__ __launch_bounds__(192) void crf_chunk(
    const float* __restrict__ feats, const float* __restrict__ trans,
    float* __restrict__ Mc)
{
  __shared__ float tr[144];
  __shared__ float fb[128][12];
  __shared__ float accA[156];
  __shared__ float accB[156];
  const int tid = threadIdx.x;
  const int cb  = blockIdx.x;
  if (tid < 144) tr[tid] = trans[tid];
  for (int i = tid; i < 128 * 12; i += 192)
    fb[i / 12][i % 12] = feats[(size_t)cb * 128 * 12 + i];
  __syncthreads();

  const int ii = tid / 12, jj = tid % 12;
  const bool act = tid < 144;
  float* cur = accA;
  float* nxt = accB;
  if (act) cur[ii * 13 + jj] = tr[ii * 12 + jj] + fb[0][ii];
  __syncthreads();

  for (int t = 1; t < 128; ++t) {
    if (act) {
      float v[12];
      float m = FNEG * 4.f;
#pragma unroll
      for (int k = 0; k < 12; ++k) {
        v[k] = tr[ii * 12 + k] + cur[k * 13 + jj];
        m = fmaxf(m, v[k]);
      }
      float ssum = 0.f;
#pragma unroll
      for (int k = 0; k < 12; ++k) ssum += __expf(v[k] - m);
      nxt[ii * 13 + jj] = fb[t][ii] + m + __logf(ssum);
    }
    __syncthreads();
    float* tmp = cur; cur = nxt; nxt = tmp;
  }
  if (act) Mc[(size_t)cb * 144 + ii * 12 + jj] = cur[ii * 13 + jj];
}

__global__ __launch_bounds__(64) void crf_fold(
    const float* __restrict__ Mc, const float* __restrict__ trans,
    float* __restrict__ outp)
{
  __shared__ float fv[12];
  __shared__ float nf[12];
  const int tid = threadIdx.x;
  if (tid < 12) fv[tid] = (tid == TSTART) ? 0.f : FNEG;
  __syncthreads();
  for (int cidx = 0; cidx < 128; ++cidx) {
    if (tid < 12) {
      const float* M = Mc + (size_t)cidx * 144 + tid * 12;
      float v[12];
      float m = FNEG * 4.f;
#pragma unroll
      for (int j = 0; j < 12; ++j) {
        v[j] = M[j] + fv[j];
        m = fmaxf(m, v[j]);
      }
      float s = 0.f;
#pragma unroll
      for (int j = 0; j < 12; ++j) s += __expf(v[j] - m);
      nf[tid] = m + __logf(s);
    }
    __syncthreads();
    if (tid < 12) fv[tid] = nf[tid];
    __syncthreads();
  }
  if (tid == 0) {
    float v[12];
    float m = FNEG * 4.f;
#pragma unroll
    for (int i = 0; i < 12; ++i) {
      v[i] = fv[i] + trans[TSTOP * 12 + i];
      m = fmaxf(m, v[i]);
    }
    float s = 0.f;
#pragma unroll
    for (int i = 0; i < 12; ++i) s += __expf(v[i] - m);
    outp[0] = m + __logf(s);
  }
}

// ---------------------------------------------------------------------------
extern "C" void kernel_launch(void* const* d_in, const int* in_sizes, int n_in,
                              void* d_out, int out_size, void* d_ws, size_t ws_size,
                              hipStream_t stream)
{
  (void)in_sizes; (void)n_in; (void)out_size; (void)ws_size;
  const float* x     = (const float*)d_in[0];
  const float* Wg    = (const float*)d_in[1];
  const float* bg    = (const float*)d_in[2];
  const float* Wn    = (const float*)d_in[3];
  const float* bnn   = (const float*)d_in[4];
  const float* Wl    = (const float*)d_in[5];
  const float* bl    = (const float*)d_in[6];
  const float* Wih0f = (const float*)d_in[7];
  const float* Whh0f = (const float*)d_in[8];
  const float* b0f   = (const float*)d_in[9];
  const float* Wih0b = (const float*)d_in[10];
  const float* Whh0b = (const float*)d_in[11];
  const float* b0b   = (const float*)d_in[12];
  const float* Wih1f = (const float*)d_in[13];
  const float* Whh1f = (const float*)d_in[14];
  const float* b1f   = (const float*)d_in[15];
  const float* Wih1b = (const float*)d_in[16];
  const float* Whh1b = (const float*)d_in[17];
  const float* b1b   = (const float*)d_in[18];
  const float* Wtag  = (const float*)d_in[19];
  const float* btag  = (const float*)d_in[20];
  const float* trans = (const float*)d_in[21];
  const float* h0    = (const float*)d_in[22];
  const float* c0    = (const float*)d_in[23];

  char* ws = (char*)d_ws;
  size_t off = 0;
  auto alloc = [&](size_t bytes) -> void* {
    void* p = ws + off;
    off += (bytes + 255) & ~(size_t)255;
    return p;
  };
  float* xhw1  = (float*)alloc((size_t)S_LEN * DIM * 4);        // 26.2 MB
  float* xhw2  = (float*)alloc((size_t)S_LEN * DIM * 4);        // 26.2 MB
  u16*   Pbuf  = (u16*)alloc((size_t)2 * S_LEN * 1024 * 2);     // 64 MB
  float* X1    = (float*)alloc((size_t)S_LEN * 512 * 4);        // 33.6 MB
  int*   Wq8   = (int*)alloc((size_t)4 * 1024 * 64 * 4);        // 1 MB
  float* Wsc   = (float*)alloc((size_t)4096 * 4);
  int*   h0qb  = (int*)alloc((size_t)4 * 64 * 4);
  float* h0sb  = (float*)alloc((size_t)4 * 4);
  float* feats = (float*)alloc((size_t)S_LEN * NTAG * 4);
  float* Mc    = (float*)alloc((size_t)128 * 144 * 4);

  // 1) int8-quantize recurrent weights + h0
  quant_whh<<<1025, 256, 0, stream>>>(Whh0f, Whh0b, Whh1f, Whh1b, h0,
                                      Wq8, Wsc, h0qb, h0sb);

  // 2) highway x2
  dim3 gHW(S_LEN / 64, 7);
  hw_kernel<<<gHW, 256, 0, stream>>>(x, Wg, bg, Wn, bnn, Wl, bl, xhw1);
  hw_kernel<<<gHW, 256, 0, stream>>>(xhw1, Wg + 160000, bg + 400,
                                     Wn + 160000, bnn + 400,
                                     Wl + 160000, bl + 400, xhw2);

  // 3) layer-0 input projections (f16 out)
  dim3 gP(S_LEN / 64, 16);
  gemm_kernel<<<gP, 256, 0, stream>>>(xhw2, Wih0f, b0f, nullptr, Pbuf,
                                      S_LEN, 1024, DIM);
  gemm_kernel<<<gP, 256, 0, stream>>>(xhw2, Wih0b, b0b, nullptr,
                                      Pbuf + (size_t)S_LEN * 1024,
                                      S_LEN, 1024, DIM);

  // 4) layer-0 bidirectional scan -> X1 [S,512]
  lstm_scan<<<2, 512, 0, stream>>>(Wq8, Wsc, h0qb, h0sb, c0, 0, Pbuf, X1);

  // 5) layer-1 input projections
  gemm_kernel<<<gP, 256, 0, stream>>>(X1, Wih1f, b1f, nullptr, Pbuf,
                                      S_LEN, 1024, 512);
  gemm_kernel<<<gP, 256, 0, stream>>>(X1, Wih1b, b1b, nullptr,
                                      Pbuf + (size_t)S_LEN * 1024,
                                      S_LEN, 1024, 512);

  // 6) layer-1 scan -> X1 reused as lstm_out [S,512]
  lstm_scan<<<2, 512, 0, stream>>>(Wq8 + (size_t)2 * 1024 * 64, Wsc + 2048,
                                   h0qb, h0sb, c0, 2, Pbuf, X1);

  // 7) tag projection -> feats [S,12]
  dim3 gT(S_LEN / 64, 1);
  gemm_kernel<<<gT, 256, 0, stream>>>(X1, Wtag, btag, feats, nullptr,
                                      S_LEN, NTAG, 512);

  // 8) CRF log-partition
  crf_chunk<<<128, 192, 0, stream>>>(feats, trans, Mc);
  crf_fold<<<1, 64, 0, stream>>>(Mc, trans, (float*)d_out);
}